// Round 5
// baseline (113.393 us; speedup 1.0000x reference)
//
#include <hip/hip_runtime.h>
#include <hip/hip_bf16.h>

#define BB 16
#define SS 2048
#define DD 1024
#define HH 16
#define KK 31
#define HK 496

typedef float f32x4 __attribute__((ext_vector_type(4)));
typedef __bf16 bf16x8 __attribute__((ext_vector_type(8)));

__device__ __forceinline__ unsigned f2bf(float x) {
  unsigned u = __float_as_uint(x);
  unsigned r = u + 0x7FFFu + ((u >> 16) & 1u);
  return r >> 16;
}

// ---------------- prep: W_q (f32, D x 496) -> bf16 image, padded N=512.
// Bimg[ks][w][n][g][qq][e] = W[k=ks*32+g*8+e][col=w*64+n*16+qq]
__global__ void prep_kernel(const float* __restrict__ Wq,
                            unsigned short* __restrict__ Bimg) {
  int idx = blockIdx.x * 256 + threadIdx.x;  // < 524288
  int e = idx & 7;
  int qq = (idx >> 3) & 15;
  int g = (idx >> 7) & 3;
  int n = (idx >> 9) & 3;
  int w = (idx >> 11) & 7;
  int ks = idx >> 14;
  int k = ks * 32 + g * 8 + e;
  int c = w * 64 + n * 16 + qq;
  int h = c >> 5, j = c & 31;
  float v = (j < KK) ? Wq[k * HK + h * KK + j] : 0.f;
  Bimg[idx] = (unsigned short)f2bf(v);
}

// ---------------- ksum: (B,S,H) = sum over 64 channels per head, f32
__global__ void ksum_kernel(const float* __restrict__ key,
                            float* __restrict__ ksum) {
  const int row = blockIdx.x;
  const int tid = threadIdx.x;
  const float4 v = reinterpret_cast<const float4*>(key + (size_t)row * DD)[tid];
  float p = v.x + v.y + v.z + v.w;
  p += __shfl_xor(p, 1);
  p += __shfl_xor(p, 2);
  p += __shfl_xor(p, 4);
  p += __shfl_xor(p, 8);
  if ((tid & 15) == 0) ksum[(size_t)row * HH + (tid >> 4)] = p;
}

// ---------------- G: GEMM only. BM=128, BN=512, 8 waves N-split.
// Two K-halves: stage A-image (128 rows x 512 k) bf16 in 128KB LDS, then
// 16 K-steps with B direct from L2 (1-step register prefetch).
// Writes weights bf16 wout[b][t][col=h*32+j] (+bq bias; col j==31 -> 0).
__global__ __launch_bounds__(512, 2) void gemm_kernel(
    const float* __restrict__ q, const float* __restrict__ bq,
    const unsigned short* __restrict__ Bimg, unsigned short* __restrict__ wout) {
  extern __shared__ char smem[];
  const int tid = threadIdx.x;
  const int w = tid >> 6, lane = tid & 63;
  const int g = lane >> 4, qq = lane & 15;
  const int bid = blockIdx.x;
  const int bb = bid >> 4;
  const int t0 = (bid & 15) << 7;

  const float* qblk = q + ((size_t)(bb * SS + t0)) * DD;
  const unsigned short* bbase = Bimg + w * 2048 + lane * 8;

  f32x4 acc[8][4];
#pragma unroll
  for (int m = 0; m < 8; ++m)
#pragma unroll
    for (int n = 0; n < 4; ++n) acc[m][n] = (f32x4){0.f, 0.f, 0.f, 0.f};

  auto loadB = [&](int ks, bf16x8* pB) {
    const unsigned short* p = bbase + (size_t)ks * 16384;
#pragma unroll
    for (int n = 0; n < 4; ++n)
      pB[n] = *reinterpret_cast<const bf16x8*>(p + n * 512);
  };

#pragma unroll
  for (int hf = 0; hf < 2; ++hf) {
    __syncthreads();  // previous half's LDS reads done before overwrite
    // stage A K-half: linear 1KB-per-wave-instr global reads
#pragma unroll 8
    for (int it = 0; it < 32; ++it) {
      const int gidx = it * 512 + tid;
      const int row = gidx >> 7;
      const int c16 = gidx & 127;
      const float4 v =
          reinterpret_cast<const float4*>(qblk)[row * 256 + hf * 128 + c16];
      const int ksl = c16 >> 3, gg = (c16 >> 1) & 3, h4 = c16 & 1;
      const unsigned u0 = f2bf(v.x) | (f2bf(v.y) << 16);
      const unsigned u1 = f2bf(v.z) | (f2bf(v.w) << 16);
      const int byte =
          (ksl * 8192 + gg * 2048 + row * 16 + h4 * 8) ^ ((ksl & 7) << 4);
      *reinterpret_cast<uint2*>(smem + byte) = make_uint2(u0, u1);
    }
    __syncthreads();

    bf16x8 pB0[4], pB1[4];
    loadB(hf * 16, pB0);
#pragma unroll
    for (int ksl = 0; ksl < 16; ++ksl) {
      bf16x8* cur = (ksl & 1) ? pB1 : pB0;
      bf16x8* nxt = (ksl & 1) ? pB0 : pB1;
      if (ksl < 15) loadB(hf * 16 + ksl + 1, nxt);  // issue before MFMAs
      const int sw = (ksl & 7) << 4;
      bf16x8 af[8];
#pragma unroll
      for (int m = 0; m < 8; ++m) {
        const int byte = (ksl * 8192 + g * 2048 + (m * 16 + qq) * 16) ^ sw;
        af[m] = *reinterpret_cast<const bf16x8*>(smem + byte);
      }
#pragma unroll
      for (int m = 0; m < 8; ++m)
#pragma unroll
        for (int n = 0; n < 4; ++n)
          acc[m][n] = __builtin_amdgcn_mfma_f32_16x16x32_bf16(af[m], cur[n],
                                                              acc[m][n], 0, 0, 0);
    }
  }

  // epilogue: add bq, store bf16 weights [b][t][col]
  float bqv[4];
#pragma unroll
  for (int n = 0; n < 4; ++n) {
    int c = w * 64 + n * 16 + qq;
    int h = c >> 5, j = c & 31;
    bqv[n] = (j < KK) ? bq[h * KK + j] : 0.f;  // padded col -> acc 0 + 0
  }
#pragma unroll
  for (int m = 0; m < 8; ++m)
#pragma unroll
    for (int n = 0; n < 4; ++n)
#pragma unroll
      for (int r = 0; r < 4; ++r) {
        const int t = t0 + m * 16 + g * 4 + r;
        const int col = w * 64 + n * 16 + qq;
        wout[(((size_t)(bb * SS + t)) << 9) + col] =
            (unsigned short)f2bf(acc[m][n][r] + bqv[n]);
      }
}

// ---------------- C: conv from weights + ksum -> out (B,H,S)
__global__ __launch_bounds__(512) void conv_kernel(
    const unsigned short* __restrict__ wout, const float* __restrict__ ksum,
    const float* __restrict__ convb, float* __restrict__ out) {
  __shared__ float kl[160 * 17];
  const int tid = threadIdx.x;
  const int bid = blockIdx.x;
  const int bb = bid >> 4;
  const int t0 = (bid & 15) << 7;

  for (int i = tid; i < 160 * 16; i += 512) {
    int trow = i >> 4, h = i & 15;
    int t = t0 + trow - 15;
    kl[trow * 17 + h] = (t >= 0 && t < SS) ? ksum[((size_t)bb * SS + t) * HH + h] : 0.f;
  }
  __syncthreads();

#pragma unroll
  for (int it = 0; it < 4; ++it) {
    const int i = it * 512 + tid;
    const int h = i >> 7, row = i & 127;  // wave-uniform h, lane-linear row
    const unsigned short* wp =
        wout + (((size_t)(bb * SS + t0 + row)) << 9) + h * 32;
    float s = 0.f;
#pragma unroll
    for (int u = 0; u < 4; ++u) {
      bf16x8 wv = *reinterpret_cast<const bf16x8*>(wp + u * 8);
#pragma unroll
      for (int e = 0; e < 8; ++e) {
        const int j = u * 8 + e;
        s += (float)wv[e] * kl[(row + j) * 17 + h];
      }
    }
    out[((size_t)(bb * HH + h)) * SS + t0 + row] = s + convb[h];
  }
}

// ---------------- fallback: R4 fused kernel (used only if ws is small)
__global__ __launch_bounds__(512, 2) void mca_kernel(
    const float* __restrict__ q, const float* __restrict__ bq,
    const float* __restrict__ convb, const float* __restrict__ ksum,
    const unsigned short* __restrict__ Bimg, float* __restrict__ out) {
  extern __shared__ char smem[];
  const int tid = threadIdx.x;
  const int w = tid >> 6, lane = tid & 63;
  const int g = lane >> 4, qq = lane & 15;
  const int bid = blockIdx.x;
  const int bb = bid >> 5;
  const int t0 = (bid & 31) << 6;

  const float* qblk = q + ((size_t)(bb * SS + t0)) * DD;
  const unsigned short* bbase = Bimg + w * 2048 + lane * 8;

  f32x4 acc[4][4];
#pragma unroll
  for (int m = 0; m < 4; ++m)
#pragma unroll
    for (int n = 0; n < 4; ++n) acc[m][n] = (f32x4){0.f, 0.f, 0.f, 0.f};

#pragma unroll 8
  for (int it = 0; it < 32; ++it) {
    const int gidx = it * 512 + tid;
    const int row = gidx >> 8;
    const int c16 = gidx & 255;
    const float4 v = reinterpret_cast<const float4*>(qblk)[gidx];
    const int ks = c16 >> 3, gg = (c16 >> 1) & 3, half = c16 & 1;
    const unsigned u0 = f2bf(v.x) | (f2bf(v.y) << 16);
    const unsigned u1 = f2bf(v.z) | (f2bf(v.w) << 16);
    const int byte = (ks * 4096 + gg * 1024 + row * 16 + half * 8) ^ ((ks & 7) << 4);
    *reinterpret_cast<uint2*>(smem + byte) = make_uint2(u0, u1);
  }
  __syncthreads();

  auto loadB = [&](int ks, bf16x8* pB) {
    const unsigned short* p = bbase + (size_t)ks * 16384;
#pragma unroll
    for (int n = 0; n < 4; ++n)
      pB[n] = *reinterpret_cast<const bf16x8*>(p + n * 512);
  };
  auto compute = [&](int ks, const bf16x8* pB) {
    const int sw = (ks & 7) << 4;
    bf16x8 af[4];
#pragma unroll
    for (int m = 0; m < 4; ++m) {
      const int byte = (ks * 4096 + g * 1024 + (m * 16 + qq) * 16) ^ sw;
      af[m] = *reinterpret_cast<const bf16x8*>(smem + byte);
    }
#pragma unroll
    for (int m = 0; m < 4; ++m)
#pragma unroll
      for (int n = 0; n < 4; ++n)
        acc[m][n] = __builtin_amdgcn_mfma_f32_16x16x32_bf16(af[m], pB[n], acc[m][n], 0, 0, 0);
  };

  bf16x8 pBa[4], pBb[4];
  loadB(0, pBa);
#pragma unroll
  for (int k2 = 0; k2 < 16; ++k2) {
    loadB(2 * k2 + 1, pBb);
    compute(2 * k2, pBa);
    if (k2 < 15) loadB(2 * k2 + 2, pBa);
    compute(2 * k2 + 1, pBb);
  }

  float bqv[4];
#pragma unroll
  for (int n = 0; n < 4; ++n) {
    int c = w * 64 + n * 16 + qq;
    int h = c >> 5, j = c & 31;
    bqv[n] = (j < KK) ? bq[h * KK + j] : 0.f;
  }
  float cb[2] = {convb[w * 2], convb[w * 2 + 1]};

  __syncthreads();
  float* kl = reinterpret_cast<float*>(smem);
  for (int i = tid; i < 96 * 16; i += 512) {
    int trow = i >> 4, h = i & 15;
    int t = t0 + trow - 15;
    kl[trow * 17 + h] = (t >= 0 && t < SS) ? ksum[((size_t)bb * SS + t) * HH + h] : 0.f;
  }
  __syncthreads();

#pragma unroll
  for (int m = 0; m < 4; ++m) {
    float part[4][2];
#pragma unroll
    for (int r = 0; r < 4; ++r) {
      part[r][0] = 0.f;
      part[r][1] = 0.f;
    }
#pragma unroll
    for (int n = 0; n < 4; ++n) {
      const int hp = n >> 1;
      const int j = (n & 1) * 16 + qq;
      const int h = w * 2 + hp;
#pragma unroll
      for (int r = 0; r < 4; ++r) {
        const int tl = m * 16 + g * 4 + r;
        part[r][hp] += (acc[m][n][r] + bqv[n]) * kl[(tl + j) * 17 + h];
      }
    }
#pragma unroll
    for (int r = 0; r < 4; ++r)
#pragma unroll
      for (int hp = 0; hp < 2; ++hp) {
        float v = part[r][hp];
        v += __shfl_xor(v, 1);
        v += __shfl_xor(v, 2);
        v += __shfl_xor(v, 4);
        v += __shfl_xor(v, 8);
        part[r][hp] = v;
      }
    if (qq < 4) {
      const int r = qq;
      const int t = t0 + m * 16 + g * 4 + r;
#pragma unroll
      for (int hp = 0; hp < 2; ++hp)
        out[((size_t)bb * HH + w * 2 + hp) * SS + t] = part[r][hp] + cb[hp];
    }
  }
}

extern "C" void kernel_launch(void* const* d_in, const int* in_sizes, int n_in,
                              void* d_out, int out_size, void* d_ws, size_t ws_size,
                              hipStream_t stream) {
  const float* q   = (const float*)d_in[0];
  const float* key = (const float*)d_in[1];
  const float* Wq  = (const float*)d_in[4];
  const float* bq  = (const float*)d_in[5];
  const float* cvb = (const float*)d_in[6];
  float* out = (float*)d_out;

  float* ksum = (float*)d_ws;                                        // 2 MB
  unsigned short* Bimg = (unsigned short*)((char*)d_ws + (2 << 20)); // 1 MB
  unsigned short* wout = (unsigned short*)((char*)d_ws + (3 << 20)); // 32 MB

  prep_kernel<<<2048, 256, 0, stream>>>(Wq, Bimg);
  ksum_kernel<<<BB * SS, 256, 0, stream>>>(key, ksum);

  if (ws_size >= (size_t)(36 << 20)) {
    hipFuncSetAttribute((const void*)gemm_kernel,
                        hipFuncAttributeMaxDynamicSharedMemorySize, 131072);
    gemm_kernel<<<BB * (SS / 128), 512, 131072, stream>>>(q, bq, Bimg, wout);
    conv_kernel<<<BB * (SS / 128), 512, 0, stream>>>(wout, ksum, cvb, out);
  } else {
    hipFuncSetAttribute((const void*)mca_kernel,
                        hipFuncAttributeMaxDynamicSharedMemorySize, 131072);
    mca_kernel<<<BB * (SS / 64), 512, 131072, stream>>>(q, bq, cvb, ksum, Bimg, out);
  }
}

// Round 6
// 90.305 us; speedup vs baseline: 1.2557x; 1.2557x over previous
//
#include <hip/hip_runtime.h>
#include <hip/hip_bf16.h>

#define BB 16
#define SS 2048
#define DD 1024
#define HH 16
#define KK 31
#define HK 496

typedef float f32x16 __attribute__((ext_vector_type(16)));
typedef __bf16 bf16x8 __attribute__((ext_vector_type(8)));

__device__ __forceinline__ unsigned f2bf(float x) {
  unsigned u = __float_as_uint(x);
  unsigned r = u + 0x7FFFu + ((u >> 16) & 1u);
  return r >> 16;
}

// ---------------- prep: W_q (f32, D x 496) -> bf16 image, padded N=512.
// Per-wave direct fragment loads for mfma_32x32x16:
// Bimg[ks][slice][w][nt][lane][e] = W[k][col], k = ks*32+slice*16+(lane>>5)*8+e,
// col = w*64 + nt*32 + (lane&31)
__global__ void prep_kernel(const float* __restrict__ Wq,
                            unsigned short* __restrict__ Bimg) {
  int idx = blockIdx.x * 256 + threadIdx.x;  // < 524288
  int e = idx & 7;
  int lane = (idx >> 3) & 63;
  int nt = (idx >> 9) & 1;
  int w = (idx >> 10) & 7;
  int slice = (idx >> 13) & 1;
  int ks = idx >> 14;
  int k = ks * 32 + slice * 16 + (lane >> 5) * 8 + e;
  int c = w * 64 + nt * 32 + (lane & 31);
  int h = c >> 5, j = c & 31;
  float v = (j < KK) ? Wq[k * HK + h * KK + j] : 0.f;
  Bimg[idx] = (unsigned short)f2bf(v);
}

// ---------------- ksum: (B,S,H) = sum over 64 channels per head, f32
__global__ void ksum_kernel(const float* __restrict__ key,
                            float* __restrict__ ksum) {
  const int row = blockIdx.x;
  const int tid = threadIdx.x;
  const float4 v = reinterpret_cast<const float4*>(key + (size_t)row * DD)[tid];
  float p = v.x + v.y + v.z + v.w;
  p += __shfl_xor(p, 1);
  p += __shfl_xor(p, 2);
  p += __shfl_xor(p, 4);
  p += __shfl_xor(p, 8);
  if ((tid & 15) == 0) ksum[(size_t)row * HH + (tid >> 4)] = p;
}

// ---------------- fused GEMM (32x32x16 bf16 MFMA) + conv + transpose
// BM=64, BN=512, BK=32, 8 waves N-split (64 cols each as 2x 32-col head-tiles)
// A: 8KB LDS dbuf, contiguous conflict-free fragments. B: global->VGPR direct.
__global__ __launch_bounds__(512, 4) void mca_kernel(
    const float* __restrict__ q, const float* __restrict__ bq,
    const float* __restrict__ convb, const float* __restrict__ ksum,
    const unsigned short* __restrict__ Bimg, float* __restrict__ out) {
  __shared__ char smem[8192];
  const int tid = threadIdx.x;
  const int w = tid >> 6, lane = tid & 63;
  const int l31 = lane & 31, hi = lane >> 5;
  const int bid = blockIdx.x;
  const int bb = bid >> 5;
  const int t0 = (bid & 31) << 6;

  char* const bA0 = smem;
  char* const bA1 = smem + 4096;

  const float* qblk = q + ((size_t)(bb * SS + t0)) * DD;
  // frag(slice,nt) at Bimg + ks*16384 + ((slice*8 + w)*2 + nt)*512 + lane*8
  const unsigned short* bbase = Bimg + (((size_t)w * 2) << 9) + lane * 8;

  f32x16 acc[2][2];
#pragma unroll
  for (int mt = 0; mt < 2; ++mt)
#pragma unroll
    for (int nt = 0; nt < 2; ++nt)
#pragma unroll
      for (int r = 0; r < 16; ++r) acc[mt][nt][r] = 0.f;

  // A staging: thread -> (row = tid>>3, k4 = tid&7); 16B f32 -> 8B bf16
  const int arow = tid >> 3;
  const int ak4 = tid & 7;
  const int as = ak4 >> 2, ah = (ak4 >> 1) & 1, ae = ak4 & 1;
  const int abyte = as * 2048 + ah * 1024 + arow * 16 + ae * 8;

  auto issueA = [&](int ks, float4& rA) {
    rA = *reinterpret_cast<const float4*>(qblk + (size_t)arow * DD + ks * 32 + ak4 * 4);
  };
  auto writeA = [&](char* dst, const float4& rA) {
    unsigned u0 = f2bf(rA.x) | (f2bf(rA.y) << 16);
    unsigned u1 = f2bf(rA.z) | (f2bf(rA.w) << 16);
    *reinterpret_cast<uint2*>(dst + abyte) = make_uint2(u0, u1);
  };
  auto loadB = [&](int ks, bf16x8 pB[2][2]) {
    const unsigned short* p = bbase + (size_t)ks * 16384;
#pragma unroll
    for (int s = 0; s < 2; ++s)
#pragma unroll
      for (int nt = 0; nt < 2; ++nt)
        pB[s][nt] = *reinterpret_cast<const bf16x8*>(p + (s * 16 + nt) * 512);
  };
  // A frag (mt, slice): lanes read contiguous 512B runs -> conflict-free
  auto computeT = [&](const char* bufA, const bf16x8 pB[2][2]) {
#pragma unroll
    for (int s = 0; s < 2; ++s) {
      bf16x8 a[2];
#pragma unroll
      for (int mt = 0; mt < 2; ++mt)
        a[mt] = *reinterpret_cast<const bf16x8*>(
            bufA + s * 2048 + hi * 1024 + (mt * 32 + l31) * 16);
#pragma unroll
      for (int mt = 0; mt < 2; ++mt)
#pragma unroll
        for (int nt = 0; nt < 2; ++nt)
          acc[mt][nt] = __builtin_amdgcn_mfma_f32_32x32x16_bf16(
              a[mt], pB[s][nt], acc[mt][nt], 0, 0, 0);
    }
  };
  auto barrier = [&]() {
    asm volatile("s_waitcnt lgkmcnt(0)" ::: "memory");
    __builtin_amdgcn_s_barrier();
  };

  float4 rA0, rA1;
  bf16x8 pBa[2][2], pBb[2][2];

  issueA(0, rA0);
  loadB(0, pBa);
  writeA(bA0, rA0);
  barrier();

  for (int ks2 = 0; ks2 < 15; ++ks2) {
    const int ks = ks2 * 2;
    issueA(ks + 1, rA1);
    loadB(ks + 1, pBb);
    computeT(bA0, pBa);
    writeA(bA1, rA1);
    barrier();
    issueA(ks + 2, rA0);
    loadB(ks + 2, pBa);
    computeT(bA1, pBb);
    writeA(bA0, rA0);
    barrier();
  }
  issueA(31, rA1);
  loadB(31, pBb);
  computeT(bA0, pBa);
  writeA(bA1, rA1);
  barrier();
  computeT(bA1, pBb);

  // ---- epilogue: conv over j in f32; each 32-col tile = one head, j = l31
  float bqv[2], cb[2];
#pragma unroll
  for (int nt = 0; nt < 2; ++nt) {
    const int h = w * 2 + nt;
    bqv[nt] = (l31 < KK) ? bq[h * KK + l31] : 0.f;
    cb[nt] = convb[h];
  }

  __syncthreads();  // A buffers dead; reuse smem for ksum slice
  float* kl = reinterpret_cast<float*>(smem);
  for (int i = tid; i < 96 * 16; i += 512) {
    int trow = i >> 4, h = i & 15;
    int t = t0 + trow - 15;
    kl[trow * 17 + h] = (t >= 0 && t < SS) ? ksum[((size_t)bb * SS + t) * HH + h] : 0.f;
  }
  __syncthreads();

#pragma unroll
  for (int mt = 0; mt < 2; ++mt)
#pragma unroll
    for (int nt = 0; nt < 2; ++nt) {
      const int h = w * 2 + nt;
#pragma unroll
      for (int r = 0; r < 16; ++r) {
        const int tl = mt * 32 + (r & 3) + 8 * (r >> 2) + 4 * hi;
        float v = (acc[mt][nt][r] + bqv[nt]) * kl[(tl + l31) * 17 + h];
        v += __shfl_xor(v, 1);
        v += __shfl_xor(v, 2);
        v += __shfl_xor(v, 4);
        v += __shfl_xor(v, 8);
        v += __shfl_xor(v, 16);
        if (l31 == r)
          out[((size_t)(bb * HH + h)) * SS + t0 + tl] = v + cb[nt];
      }
    }
}

extern "C" void kernel_launch(void* const* d_in, const int* in_sizes, int n_in,
                              void* d_out, int out_size, void* d_ws, size_t ws_size,
                              hipStream_t stream) {
  const float* q   = (const float*)d_in[0];
  const float* key = (const float*)d_in[1];
  // d_in[2] (values) and d_in[3] (lengths) are unused by the reference
  const float* Wq  = (const float*)d_in[4];
  const float* bq  = (const float*)d_in[5];
  const float* cvb = (const float*)d_in[6];
  float* out = (float*)d_out;

  float* ksum = (float*)d_ws;                                        // 2 MB
  unsigned short* Bimg = (unsigned short*)((char*)d_ws + (2 << 20)); // 1 MB

  prep_kernel<<<2048, 256, 0, stream>>>(Wq, Bimg);
  ksum_kernel<<<BB * SS, 256, 0, stream>>>(key, ksum);
  mca_kernel<<<BB * (SS / 64), 512, 0, stream>>>(q, bq, cvb, ksum, Bimg, out);
}